// Round 8
// baseline (94.735 us; speedup 1.0000x reference)
//
#include <hip/hip_runtime.h>

// Bilateral 5x5, sigma_spatial=1.5, sigma_color=0.1, reflect pad.
// [2,3,1024,1024] fp32 = 6 independent 1024x1024 images.
//
// Schraudolph magic-window weights (no cvt, no transcendental):
//   tile pre-scaled by S13 = sqrt(2^13*50*log2(e));
//   t = fma(-u,u,Cij), Cij = 12582912 + 2^13*(127-0.043+lk2_ij)
//   t in [2^23,2^24): fma rounding IS round-to-int; w = bitcast(bits(t)<<10).
// Center tap rides the approx pipe; exactness restored by accumulator-init
// bias CORR = K2C - decode(CD(2,2)).
//
// R7 restructure: 4 output columns per thread. Thread (ttx,tty) covers
// output cols 4ttx..4ttx+3, rows 4tty..4tty+3 of a 64x64 tile. Per window
// row it needs padded cols 4ttx..4ttx+7 = two 16B-aligned quads ->
// 2x ds_read_b128 per 4 pixels per row (was ~5 scalar ds_read_b32 / px).
// Window = 5 rows x 2 float4, EXPLICITLY rotated named values (no
// circular indexing -> guaranteed SROA/registers; R3-R6 VGPR_Count=24-28
// proved the old window was silently rematerialized from LDS).

#define TX 64
#define TY 64
#define PAD 2
#define LW 68       // padded row stride: 68 floats = 17 float4 (16B aligned)
#define LH 68
#define BX 16
#define BYW 16

typedef float f4 __attribute__((ext_vector_type(4)));

__device__ __forceinline__ float decode1(float t) {
    return __builtin_bit_cast(float, __builtin_bit_cast(unsigned, t) << 10);
}

__global__ __launch_bounds__(256) void bilateral_kernel(
    const float* __restrict__ in, float* __restrict__ out, int H, int W)
{
    const int z  = blockIdx.z;
    const int x0 = blockIdx.x * TX;
    const int y0 = blockIdx.y * TY;
    const int ttx = threadIdx.x;     // 0..15 -> output cols 4ttx..4ttx+3
    const int tty = threadIdx.y;     // 0..15 -> output rows 4tty..4tty+3
    const int tid = tty * BX + ttx;

    const float S13  = 768.744433f;  // sqrt(2^13 * 50 * log2(e))
    const float SEPS = 7.68744433e-6f;

    __shared__ float tile[LH * LW];
    const float* img = in + (size_t)z * H * W;

    // Cooperative halo load (reflect, pad=2), pre-scaled by S13.
    for (int idx = tid; idx < LH * LW; idx += BX * BYW) {
        int r = idx / LW;
        int c = idx - r * LW;
        int gy = y0 - PAD + r;
        int gx = x0 - PAD + c;
        gy = gy < 0 ? -gy : (gy >= H ? 2 * H - 2 - gy : gy);
        gx = gx < 0 ? -gx : (gx >= W ? 2 * W - 2 - gx : gx);
        tile[idx] = img[(size_t)gy * W + gx] * S13;
    }
    __syncthreads();

    // log2 of normalized 1-D spatial gaussian (sigma=1.5, k=5).
    constexpr double Ld[5] = {-3.0580100, -2.0962162, -1.7756103,
                              -2.0962162, -3.0580100};
    constexpr double A13  = 8192.0;
    constexpr double CMAG = 12582912.0 + (127.0 - 0.043) * 8192.0;
#define CD(i, j) ((float)(CMAG + A13 * (Ld[i] + Ld[j])))
    const float K2C  = 0.0853118f;           // exact center weight
    const float CORR = K2C - decode1(CD(2, 2));

    const f4* tl = (const f4*)tile;          // row stride 17 quads

    // Window rows q..q+4 (padded coords), each = 2 quads (cols 4ttx..4ttx+7).
    f4 A0, B0, A1, B1, A2, B2, A3, B3;
    {
        const int rb = 4 * tty;
        A0 = tl[(rb + 0) * 17 + ttx]; B0 = tl[(rb + 0) * 17 + ttx + 1];
        A1 = tl[(rb + 1) * 17 + ttx]; B1 = tl[(rb + 1) * 17 + ttx + 1];
        A2 = tl[(rb + 2) * 17 + ttx]; B2 = tl[(rb + 2) * 17 + ttx + 1];
        A3 = tl[(rb + 3) * 17 + ttx]; B3 = tl[(rb + 3) * 17 + ttx + 1];
    }

#define TAP(p, c, C, w, v) {                                   \
        const float u_ = (p) - (c);                            \
        const float t_ = __builtin_fmaf(-u_, u_, (C));         \
        const float wt_ = decode1(t_);                         \
        (w) += wt_; (v) = __builtin_fmaf(wt_, (p), (v)); }

    // Per row i: 4 pixels x 5 taps from the 8-wide row {Ai,Bi}.
#define ROW(Ai, Bi, i) {                                                   \
        const float e0 = Ai.x, e1 = Ai.y, e2 = Ai.z, e3 = Ai.w;            \
        const float e4 = Bi.x, e5 = Bi.y, e6 = Bi.z, e7 = Bi.w;            \
        TAP(e0, c0, CD(i,0), w0, v0) TAP(e1, c0, CD(i,1), w0, v0)          \
        TAP(e2, c0, CD(i,2), w0, v0) TAP(e3, c0, CD(i,3), w0, v0)          \
        TAP(e4, c0, CD(i,4), w0, v0)                                       \
        TAP(e1, c1, CD(i,0), w1, v1) TAP(e2, c1, CD(i,1), w1, v1)          \
        TAP(e3, c1, CD(i,2), w1, v1) TAP(e4, c1, CD(i,3), w1, v1)          \
        TAP(e5, c1, CD(i,4), w1, v1)                                       \
        TAP(e2, c2, CD(i,0), w2, v2) TAP(e3, c2, CD(i,1), w2, v2)          \
        TAP(e4, c2, CD(i,2), w2, v2) TAP(e5, c2, CD(i,3), w2, v2)          \
        TAP(e6, c2, CD(i,4), w2, v2)                                       \
        TAP(e3, c3, CD(i,0), w3, v3) TAP(e4, c3, CD(i,1), w3, v3)          \
        TAP(e5, c3, CD(i,2), w3, v3) TAP(e6, c3, CD(i,3), w3, v3)          \
        TAP(e7, c3, CD(i,4), w3, v3) }

    f4* outq = (f4*)out;

#pragma unroll
    for (int q = 0; q < 4; ++q) {
        const int r4 = 4 * tty + q + 4;
        const f4 A4 = tl[r4 * 17 + ttx];
        const f4 B4 = tl[r4 * 17 + ttx + 1];

        // Centers: element k+2 of the middle row (A2,B2).
        const float c0 = A2.z, c1 = A2.w, c2 = B2.x, c3 = B2.y;

        float w0 = CORR, v0 = CORR * c0;
        float w1 = CORR, v1 = CORR * c1;
        float w2 = CORR, v2 = CORR * c2;
        float w3 = CORR, v3 = CORR * c3;

        ROW(A0, B0, 0)
        ROW(A1, B1, 1)
        ROW(A2, B2, 2)
        ROW(A3, B3, 3)
        ROW(A4, B4, 4)

        const float i0 = __builtin_amdgcn_rcpf(__builtin_fmaf(S13, w0, SEPS));
        const float i1 = __builtin_amdgcn_rcpf(__builtin_fmaf(S13, w1, SEPS));
        const float i2 = __builtin_amdgcn_rcpf(__builtin_fmaf(S13, w2, SEPS));
        const float i3 = __builtin_amdgcn_rcpf(__builtin_fmaf(S13, w3, SEPS));

        const int gy = y0 + 4 * tty + q;
        outq[(((size_t)z * H + gy) * W + x0) / 4 + ttx] =
            f4{v0 * i0, v1 * i1, v2 * i2, v3 * i3};

        // Rotate the window down one row (SSA-renamed, no moves).
        A0 = A1; B0 = B1;
        A1 = A2; B1 = B2;
        A2 = A3; B2 = B3;
        A3 = A4; B3 = B4;
    }
#undef ROW
#undef TAP
#undef CD
}

extern "C" void kernel_launch(void* const* d_in, const int* in_sizes, int n_in,
                              void* d_out, int out_size, void* d_ws, size_t ws_size,
                              hipStream_t stream) {
    const float* img = (const float*)d_in[0];
    float* out = (float*)d_out;

    const int B = 2, C = 3, H = 1024, W = 1024;
    dim3 block(BX, BYW, 1);
    dim3 grid(W / TX, H / TY, B * C);   // 16 x 16 x 6 = 1536 blocks
    bilateral_kernel<<<grid, block, 0, stream>>>(img, out, H, W);
}

// Round 12
// 94.087 us; speedup vs baseline: 1.0069x; 1.0069x over previous
//
#include <hip/hip_runtime.h>

// Bilateral 5x5, sigma_spatial=1.5, sigma_color=0.1, reflect pad.
// [2,3,1024,1024] fp32 = 6 independent 1024x1024 images.
//
// R11 (= R10 + VOP3P shift fix): fp16-packed Schraudolph taps.
//   LDS tile in fp16, pre-scaled by SC = sqrt(32*50*log2(e)) = 48.0449.
//   f16 magic window [1024,2048) (ulp=1): t = pk_fma(-u,u,C),
//   C(i,j) = 1024 + 32*(15-0.043+lk2_ij); clamp pk_max(t,1024);
//   decode = v_pk_lshlrev_b16 by {5,5}: 0x6400<<5 wraps to 0x8000, so
//   weights decode NEGATED (w = -2^x); signs cancel in the final ratio.
//   !! R10 bug: scalar inline const 5 in VOP3P gives the HIGH lane
//   op_sel_hi's hi16(5)=0 -> no shift -> undecoded ~1300 weights -> inf.
//   Fix: shift operand is a broadcast VGPR pair 0x00050005.
// Accumulate in f16 pairs, f32 epilogue.
// Pairing: same-pixel adjacent-j taps = natural half2 dwords; odd pixels
// use pair-shifted copies ((lo>>16)|(hi<<16), 3/row). 5th-column taps
// pair across pixels (0,1)/(2,3) with center pair = row2.d1/.d2 as-is.
// Center tap rides the approx pipe; exactness restored by accumulator
// init CORR = w22_approx - K2C (positive, since sums are negated).

#define TX 64
#define TY 64
#define PAD 2
#define BX 16
#define BYW 16
#define LSTRIDE 40   // dwords per LDS row (80 halves = 160 B)
#define LROWS 68
#define LDW 34       // used dwords per row (68 halves)

typedef float f4 __attribute__((ext_vector_type(4)));
typedef _Float16 h2 __attribute__((ext_vector_type(2)));
typedef unsigned int u32;

__device__ __forceinline__ h2 bch(u32 u) {
    return __builtin_bit_cast(h2, u);
}
__device__ __forceinline__ u32 pk_shl5(h2 t) {
    u32 r, x = __builtin_bit_cast(u32, t);
    // shift amount as broadcast VGPR pair {5,5}: correct in BOTH lanes
    asm("v_pk_lshlrev_b16 %0, %1, %2" : "=v"(r) : "v"(0x00050005u), "v"(x));
    return r;
}
__device__ __forceinline__ u32 shr16pair(u32 lo, u32 hi) {
    return (lo >> 16) | (hi << 16);   // {hi16(lo), lo16(hi)}
}

// log2 of normalized 1-D spatial gaussian (sigma=1.5, k=5).
constexpr double Lg[5] = {-3.0580100, -2.0962162, -1.7756103,
                          -2.0962162, -3.0580100};
constexpr unsigned short cbits(int i, int j) {
    // f16 bits of C = 1024 + s, s = 32*(15-0.043+Lg[i]+Lg[j]) (ulp=1 window)
    double s = 32.0 * (14.957 + Lg[i] + Lg[j]);
    return (unsigned short)(0x6400 + (int)(s + 0.5));
}
constexpr u32 cpack(int i, int ja, int jb) {
    return (u32)cbits(i, ja) | ((u32)cbits(i, jb) << 16);
}

struct Row { u32 d0, d1, d2, d3, s0, s1, s2; };

__global__ __launch_bounds__(256) void bilateral_kernel(
    const float* __restrict__ in, float* __restrict__ out, int H, int W)
{
    const int z   = blockIdx.z;
    const int x0  = blockIdx.x * TX;
    const int y0  = blockIdx.y * TY;
    const int ttx = threadIdx.x;   // 0..15 -> output cols 4ttx..4ttx+3
    const int tty = threadIdx.y;   // 0..15 -> output rows 4tty..4tty+3
    const int tid = tty * BX + ttx;

    const float SC    = 48.0449019f;     // sqrt(32 * 50 * log2(e))
    const float SEPS2 = 4.80449019e-7f;  // SC * 1e-8

    __shared__ u32 lds[LROWS * LSTRIDE];
    const float* img = in + (size_t)z * H * W;

    // Stage reflect-padded tile as fp16 pairs, pre-scaled by SC.
    for (int idx = tid; idx < LROWS * LDW; idx += BX * BYW) {
        int r = idx / LDW;
        int d = idx - r * LDW;
        int gy  = y0 - PAD + r;
        int gxa = x0 - PAD + 2 * d;
        int gxb = gxa + 1;
        gy  = gy  < 0 ? -gy  : (gy  >= H ? 2 * H - 2 - gy  : gy);
        gxa = gxa < 0 ? -gxa : (gxa >= W ? 2 * W - 2 - gxa : gxa);
        gxb = gxb < 0 ? -gxb : (gxb >= W ? 2 * W - 2 - gxb : gxb);
        const float a = img[(size_t)gy * W + gxa] * SC;
        const float b = img[(size_t)gy * W + gxb] * SC;
        lds[r * LSTRIDE + d] =
            __builtin_bit_cast(u32, __builtin_amdgcn_cvt_pkrtz(a, b));
    }
    __syncthreads();

    const h2 CLMP = bch(0x64006400u);        // {1024, 1024}
    // center-exactness correction: w22_approx(0.0878906) - K2C(0.0853113),
    // positive because accumulators hold NEGATED sums.
    const h2 CORR2 = h2{(_Float16)0.0025793f, (_Float16)0.0f};

    // Load a window row: 8 halves (4 dwords) + 3 pair-shifted copies.
    auto load_row = [&](int r) -> Row {
        Row R;
        const u32* p = lds + r * LSTRIDE + 2 * ttx;
        uint2 a = *(const uint2*)p;
        uint2 b = *(const uint2*)(p + 2);
        R.d0 = a.x; R.d1 = a.y; R.d2 = b.x; R.d3 = b.y;
        R.s0 = shr16pair(R.d0, R.d1);   // {e1,e2}
        R.s1 = shr16pair(R.d1, R.d2);   // {e3,e4}
        R.s2 = shr16pair(R.d2, R.d3);   // {e5,e6}
        return R;
    };

    const int rb = 4 * tty;
    Row W0 = load_row(rb + 0);
    Row W1 = load_row(rb + 1);
    Row W2 = load_row(rb + 2);
    Row W3 = load_row(rb + 3);

#define PKTAP(pD, cP, Cp, ws, vs) {                                  \
        const h2 u_ = (pD) - (cP);                                   \
        h2 t_ = __builtin_elementwise_fma(-u_, u_, (Cp));            \
        t_ = __builtin_elementwise_max(t_, CLMP);                    \
        const h2 w_ = bch(pk_shl5(t_));                              \
        (ws) = (ws) + w_;                                            \
        (vs) = __builtin_elementwise_fma(w_, (pD), (vs)); }

#define ROWI(R, i) {                                                      \
        const h2 C01 = bch(cpack(i, 0, 1));                               \
        const h2 C23 = bch(cpack(i, 2, 3));                               \
        const h2 C44 = bch(cpack(i, 4, 4));                               \
        PKTAP(bch(R.d0), c0p, C01, ws0, vs0)                              \
        PKTAP(bch(R.d1), c0p, C23, ws0, vs0)                              \
        PKTAP(bch(R.s0), c1p, C01, ws1, vs1)                              \
        PKTAP(bch(R.s1), c1p, C23, ws1, vs1)                              \
        PKTAP(bch(R.d1), c2p, C01, ws2, vs2)                              \
        PKTAP(bch(R.d2), c2p, C23, ws2, vs2)                              \
        PKTAP(bch(R.s1), c3p, C01, ws3, vs3)                              \
        PKTAP(bch(R.s2), c3p, C23, ws3, vs3)                              \
        PKTAP(bch(R.d2), cE01, C44, wsE0, vsE0)                           \
        PKTAP(bch(R.d3), cE23, C44, wsE1, vsE1) }

    f4* outq = (f4*)out;

#pragma unroll
    for (int q = 0; q < 4; ++q) {
        const Row W4 = load_row(rb + q + 4);

        // Centers from middle row: c0..c3 = e2..e5 of W2.
        const h2 d1h = bch(W2.d1), d2h = bch(W2.d2);
        const h2 c0p = h2{d1h.x, d1h.x};
        const h2 c1p = h2{d1h.y, d1h.y};
        const h2 c2p = h2{d2h.x, d2h.x};
        const h2 c3p = h2{d2h.y, d2h.y};
        const h2 cE01 = d1h;   // {c0, c1}
        const h2 cE23 = d2h;   // {c2, c3}

        h2 ws0 = CORR2, vs0 = CORR2 * c0p;
        h2 ws1 = CORR2, vs1 = CORR2 * c1p;
        h2 ws2 = CORR2, vs2 = CORR2 * c2p;
        h2 ws3 = CORR2, vs3 = CORR2 * c3p;
        h2 wsE0 = bch(0u), vsE0 = bch(0u);
        h2 wsE1 = bch(0u), vsE1 = bch(0u);

        ROWI(W0, 0)
        ROWI(W1, 1)
        ROWI(W2, 2)
        ROWI(W3, 3)
        ROWI(W4, 4)

        // Epilogue (sums are negated-true; signs cancel in the ratio).
        const float Wf0 = (float)ws0.x + (float)ws0.y + (float)wsE0.x;
        const float Vf0 = (float)vs0.x + (float)vs0.y + (float)vsE0.x;
        const float Wf1 = (float)ws1.x + (float)ws1.y + (float)wsE0.y;
        const float Vf1 = (float)vs1.x + (float)vs1.y + (float)vsE0.y;
        const float Wf2 = (float)ws2.x + (float)ws2.y + (float)wsE1.x;
        const float Vf2 = (float)vs2.x + (float)vs2.y + (float)vsE1.x;
        const float Wf3 = (float)ws3.x + (float)ws3.y + (float)wsE1.y;
        const float Vf3 = (float)vs3.x + (float)vs3.y + (float)vsE1.y;

        const float o0 = Vf0 * __builtin_amdgcn_rcpf(__builtin_fmaf(SC, Wf0, -SEPS2));
        const float o1 = Vf1 * __builtin_amdgcn_rcpf(__builtin_fmaf(SC, Wf1, -SEPS2));
        const float o2 = Vf2 * __builtin_amdgcn_rcpf(__builtin_fmaf(SC, Wf2, -SEPS2));
        const float o3 = Vf3 * __builtin_amdgcn_rcpf(__builtin_fmaf(SC, Wf3, -SEPS2));

        const int gy = y0 + 4 * tty + q;
        outq[(((size_t)z * H + gy) * W + x0) / 4 + ttx] = f4{o0, o1, o2, o3};

        W0 = W1; W1 = W2; W2 = W3; W3 = W4;
    }
#undef ROWI
#undef PKTAP
}

extern "C" void kernel_launch(void* const* d_in, const int* in_sizes, int n_in,
                              void* d_out, int out_size, void* d_ws, size_t ws_size,
                              hipStream_t stream) {
    const float* img = (const float*)d_in[0];
    float* out = (float*)d_out;

    const int B = 2, C = 3, H = 1024, W = 1024;
    dim3 block(BX, BYW, 1);
    dim3 grid(W / TX, H / TY, B * C);   // 16 x 16 x 6 = 1536 blocks
    bilateral_kernel<<<grid, block, 0, stream>>>(img, out, H, W);
}